// Round 5
// baseline (672.314 us; speedup 1.0000x reference)
//
#include <hip/hip_runtime.h>
#include <math.h>

#define NROWS 32768
#define DIM   512
#define KCODE 8192
#define DECAYF 0.99f
#define OMDF   0.01f
#define EPSF   1e-5f
#define COMMITF 0.25f
#define MARGIN 8e-4f

typedef _Float16 half8 __attribute__((ext_vector_type(8)));
typedef _Float16 half4v __attribute__((ext_vector_type(4)));
typedef float floatx16 __attribute__((ext_vector_type(16)));

// ---------------- ws layout (float offsets), total 21372992 (~85.5 MB) ----------
// inv_in  @0        [32768]
// sV1     @32768    [4*32768]   } dead after top2_merge, overlaid by:
// sV2     @163840   [4*32768]   }   rkey u64 @32768 (65536 fl)
// sI1 u16 @294912   [4*32768u16]}   cntI @98304 [8192]  cursor @106496 [8192]
//                                   lossAcc @114688
//                                   offs @131076 [8192]  perm @139268 [32768]
// list    @360448   [32768] int
// flagCnt @393216
// inv_emb @393280   [8192]
// Xh      @401472   [8388608 fl of halves]
// Xl      @8790080  [8388608]
// Eh      @17178688 [2097152]
// El      @19275840 [2097152] -> end 21372992

__device__ __forceinline__ float block_sum_256(float v) {
    __shared__ float sm[4];
    int lane = threadIdx.x & 63, wave = threadIdx.x >> 6;
    #pragma unroll
    for (int off = 32; off; off >>= 1) v += __shfl_down(v, off);
    if (lane == 0) sm[wave] = v;
    __syncthreads();
    if (threadIdx.x == 0) v = sm[0] + sm[1] + sm[2] + sm[3];
    return v; // valid on thread 0 only
}

// fused: row L2-norm + hi/lo f16 split (one read of src). 4 rows/block.
__global__ void k_norm_split(const float* __restrict__ src, float* __restrict__ inv,
                             _Float16* __restrict__ hi, _Float16* __restrict__ lo) {
    const int wave = threadIdx.x >> 6;
    const int lane = threadIdx.x & 63;
    const int row = blockIdx.x * 4 + wave;
    const float* p = src + (size_t)row * DIM;
    const float4 f1 = *(const float4*)&p[lane * 4];
    const float4 f2 = *(const float4*)&p[256 + lane * 4];
    float s = f1.x*f1.x + f1.y*f1.y + f1.z*f1.z + f1.w*f1.w
            + f2.x*f2.x + f2.y*f2.y + f2.z*f2.z + f2.w*f2.w;
    #pragma unroll
    for (int off = 32; off; off >>= 1) s += __shfl_xor(s, off);
    const float iv = 1.0f / fmaxf(sqrtf(s), 1e-12f);
    if (lane == 0) inv[row] = iv;
    const float g1[4] = {f1.x*iv, f1.y*iv, f1.z*iv, f1.w*iv};
    const float g2[4] = {f2.x*iv, f2.y*iv, f2.z*iv, f2.w*iv};
    half4v h1, h2, l1, l2;
    #pragma unroll
    for (int j = 0; j < 4; ++j) {
        const _Float16 a = (_Float16)g1[j], b = (_Float16)g2[j];
        h1[j] = a; h2[j] = b;
        l1[j] = (_Float16)((g1[j] - (float)a) * 4096.f);
        l2[j] = (_Float16)((g2[j] - (float)b) * 4096.f);
    }
    const size_t o1 = (size_t)row * DIM + lane * 4;
    *(half4v*)&hi[o1] = h1; *(half4v*)&hi[o1 + 256] = h2;
    *(half4v*)&lo[o1] = l1; *(half4v*)&lo[o1 + 256] = l2;
}

__device__ __forceinline__ void gld16(const _Float16* g, _Float16* l) {
    __builtin_amdgcn_global_load_lds(
        (const __attribute__((address_space(1))) void*)g,
        (__attribute__((address_space(3))) void*)l, 16, 0, 0);
}

__device__ __forceinline__ void top2_upd(float v, int i, float& v1, int& i1, float& v2) {
    if (v > v1) { v2 = v1; v1 = v; i1 = i; }
    else        { v2 = fmaxf(v2, v); }
}

// hi-only f16 screening. Block: 128 codes x 128 rows, wave tile 64x64 (m=2,n=2).
// acc = 64 AGPR -> ~130 regs/wave -> 3 waves/SIMD. LDS 32KB -> 3 blocks/CU.
// grid (256 row-tiles, 4 code-splits of 2048).
__launch_bounds__(256, 3)
__global__ void k_hi(const _Float16* __restrict__ Xh, const _Float16* __restrict__ Eh,
                     float* __restrict__ sV1, float* __restrict__ sV2,
                     unsigned short* __restrict__ sI1) {
    __shared__ __align__(16) _Float16 lds[16384];   // E[128][64] @0, X[128][64] @8192

    const int tid  = threadIdx.x;
    const int w    = tid >> 6;
    const int lane = tid & 63;
    const int wc = w & 1, wr = w >> 1;
    const int c = lane & 31, h = lane >> 5;
    const int rowBase = blockIdx.x * 128;
    const int split   = blockIdx.y;
    const int sr = lane >> 3;
    const int sg = (lane & 7) ^ (sr & 7);
    const int cx = c & 7;
    const int rowB = wr * 64 + c;

    float v1a = -1e30f, v2a = -1e30f, v1b = -1e30f, v2b = -1e30f;
    int i1a = 0, i1b = 0;

    // waves 0,1 stage E rows 0..127; waves 2,3 stage X rows 0..127.
    // LDS dst collapses to lds[w*4096 + j*512] for both regions.
    const _Float16* gbX = Xh + ((size_t)(rowBase + (w - 2) * 64 + sr) * DIM + sg * 8);
    _Float16* const dbase0 = &lds[w * 4096];

    for (int nt = 0; nt < 16; ++nt) {
        const int ntBase = split * 2048 + nt * 128;
        const _Float16* gb = (w < 2)
            ? Eh + ((size_t)(ntBase + w * 64 + sr) * DIM + sg * 8)
            : gbX;

        floatx16 acc00, acc01, acc10, acc11;
        #pragma unroll
        for (int r = 0; r < 16; ++r) { acc00[r]=0.f; acc01[r]=0.f; acc10[r]=0.f; acc11[r]=0.f; }

        for (int chunk = 0; chunk < 8; ++chunk) {
            #pragma unroll
            for (int j = 0; j < 8; ++j)
                gld16(gb + j * 4096 + chunk * 64, dbase0 + j * 512);
            __syncthreads();
            #pragma unroll
            for (int ks = 0; ks < 4; ++ks) {
                const int so = ((ks * 2 + h) ^ cx) * 8;
                const half8 a0 = *(const half8*)&lds[(wc * 64 + c) * 64 + so];
                const half8 a1 = *(const half8*)&lds[(wc * 64 + 32 + c) * 64 + so];
                const half8 b0 = *(const half8*)&lds[8192 + (wr * 64 + c) * 64 + so];
                const half8 b1 = *(const half8*)&lds[8192 + (wr * 64 + 32 + c) * 64 + so];
                acc00 = __builtin_amdgcn_mfma_f32_32x32x16_f16(a0, b0, acc00, 0, 0, 0);
                acc10 = __builtin_amdgcn_mfma_f32_32x32x16_f16(a1, b0, acc10, 0, 0, 0);
                acc01 = __builtin_amdgcn_mfma_f32_32x32x16_f16(a0, b1, acc01, 0, 0, 0);
                acc11 = __builtin_amdgcn_mfma_f32_32x32x16_f16(a1, b1, acc11, 0, 0, 0);
            }
            __syncthreads();
        }
        // ascending-code visit order + strict > = first-index-of-max semantics
        #pragma unroll
        for (int r = 0; r < 16; ++r) {
            const int codeSub = (r & 3) + ((r >> 2) << 3) + (h << 2);
            const int code0 = ntBase + wc * 64 + codeSub;
            top2_upd(acc00[r], code0,      v1a, i1a, v2a);
            top2_upd(acc10[r], code0 + 32, v1a, i1a, v2a);
            top2_upd(acc01[r], code0,      v1b, i1b, v2b);
            top2_upd(acc11[r], code0 + 32, v1b, i1b, v2b);
        }
    }

    // merge h-halves (same row, disjoint codes)
    {
        float ov1 = __shfl_xor(v1a, 32); int oi1 = __shfl_xor(i1a, 32); float ov2 = __shfl_xor(v2a, 32);
        if (ov1 > v1a) { v2a = fmaxf(v1a, ov2); v1a = ov1; i1a = oi1; }
        else if (ov1 == v1a) { v2a = v1a; if (oi1 < i1a) i1a = oi1; }
        else { v2a = fmaxf(v2a, ov1); }
        ov1 = __shfl_xor(v1b, 32); oi1 = __shfl_xor(i1b, 32); ov2 = __shfl_xor(v2b, 32);
        if (ov1 > v1b) { v2b = fmaxf(v1b, ov2); v1b = ov1; i1b = oi1; }
        else if (ov1 == v1b) { v2b = v1b; if (oi1 < i1b) i1b = oi1; }
        else { v2b = fmaxf(v2b, ov1); }
    }

    // wc-merge through LDS overlay (all compute reads finished at last chunk barrier)
    float* mV  = (float*)&lds[0];     // [128][2]
    float* mV2 = (float*)&lds[512];
    int*   mI  = (int*)&lds[1024];
    if (h == 0) {
        mV[rowB * 2 + wc] = v1a; mV2[rowB * 2 + wc] = v2a; mI[rowB * 2 + wc] = i1a;
        mV[(rowB + 32) * 2 + wc] = v1b; mV2[(rowB + 32) * 2 + wc] = v2b; mI[(rowB + 32) * 2 + wc] = i1b;
    }
    __syncthreads();
    if (tid < 128) {
        float v1 = mV[tid * 2], v2 = mV2[tid * 2]; int i1 = mI[tid * 2];
        float ov1 = mV[tid * 2 + 1], ov2 = mV2[tid * 2 + 1]; int oi1 = mI[tid * 2 + 1];
        if (ov1 > v1) { v2 = fmaxf(v1, ov2); v1 = ov1; i1 = oi1; }
        else if (ov1 == v1) { v2 = v1; if (oi1 < i1) i1 = oi1; }
        else { v2 = fmaxf(v2, ov1); }
        const int n = rowBase + tid;
        sV1[split * NROWS + n] = v1;
        sV2[split * NROWS + n] = v2;
        sI1[split * NROWS + n] = (unsigned short)i1;
    }
}

__global__ void k_top2_merge(const float* __restrict__ sV1, const float* __restrict__ sV2,
                             const unsigned short* __restrict__ sI1,
                             float* __restrict__ outIdx, int* __restrict__ list,
                             int* __restrict__ flagCnt) {
    const int n = blockIdx.x * 256 + threadIdx.x;
    float v1 = sV1[n], v2 = sV2[n]; int i1 = sI1[n];
    #pragma unroll
    for (int s = 1; s < 4; ++s) {
        const float b1 = sV1[s * NROWS + n], b2 = sV2[s * NROWS + n];
        const int bi = sI1[s * NROWS + n];
        if (b1 > v1) { v2 = fmaxf(v1, b2); v1 = b1; i1 = bi; }
        else         { v2 = fmaxf(v2, b1); }   // ties keep lower-split (lower code) i1
    }
    outIdx[n] = (float)i1;
    if (v1 - v2 < MARGIN) {
        const int p = atomicAdd(flagCnt, 1);
        list[p] = n;
    }
}

__device__ __forceinline__ unsigned long long encodeKey(float v, int idx) {
    unsigned u = __float_as_uint(v);
    u = (u & 0x80000000u) ? ~u : (u | 0x80000000u);
    return ((unsigned long long)u << 32) | (unsigned)(0xFFFFFFFFu - (unsigned)idx);
}

// dual-precision rescore of flagged rows (r2-identical numerics).
__launch_bounds__(256, 2)
__global__ void k_rescore(const _Float16* __restrict__ Xh, const _Float16* __restrict__ Xl,
                          const _Float16* __restrict__ Eh, const _Float16* __restrict__ El,
                          const int* __restrict__ list, const int* __restrict__ flagCnt,
                          unsigned long long* __restrict__ rkey) {
    const int cnt = *flagCnt;
    const int t = blockIdx.x & 255;
    const int s = blockIdx.x >> 8;
    if (t * 128 >= cnt) return;

    __shared__ __align__(16) _Float16 lds[32768];  // Eh|El|Xh|Xl, 8192 halves each
    __shared__ float mV[128][2];
    __shared__ int   mI[128][2];

    const int tid  = threadIdx.x;
    const int w    = tid >> 6;
    const int lane = tid & 63;
    const int wc = w & 1, wr = w >> 1;
    const int c = lane & 31, h = lane >> 5;
    const int sr = lane >> 3;
    const int sg = (lane & 7) ^ (sr & 7);
    const int rowA = wc * 64 + c;
    const int rowB = wr * 64 + c;
    const int cx = c & 7;

    int rows_j[4];
    #pragma unroll
    for (int j = 0; j < 4; ++j) {
        const int slot = t * 128 + w * 32 + j * 8 + sr;
        rows_j[j] = (slot < cnt) ? list[slot] : 0;
    }

    float best0 = -1e30f, best1 = -1e30f;
    int bi0 = 0, bi1 = 0;
    const float SC = 1.0f / 4096.0f;

    for (int nt = 0; nt < 4; ++nt) {
        const int ntBase = s * 512 + nt * 128;

        floatx16 accH00, accH01, accH10, accH11, accC00, accC01, accC10, accC11;
        #pragma unroll
        for (int r = 0; r < 16; ++r) {
            accH00[r] = 0.f; accH01[r] = 0.f; accH10[r] = 0.f; accH11[r] = 0.f;
            accC00[r] = 0.f; accC01[r] = 0.f; accC10[r] = 0.f; accC11[r] = 0.f;
        }

        for (int chunk = 0; chunk < 8; ++chunk) {
            const int kt = chunk * 64;
            #pragma unroll
            for (int j = 0; j < 4; ++j) {
                const int rl = w * 32 + j * 8 + sr;
                const size_t gE = (size_t)(ntBase + rl) * DIM + kt + sg * 8;
                const size_t gX = (size_t)rows_j[j] * DIM + kt + sg * 8;
                _Float16* dBase = &lds[(w * 32 + j * 8) * 64];
                gld16(Eh + gE, dBase);
                gld16(El + gE, dBase + 8192);
                gld16(Xh + gX, dBase + 16384);
                gld16(Xl + gX, dBase + 24576);
            }
            __syncthreads();
            #pragma unroll
            for (int ks = 0; ks < 4; ++ks) {
                const int so = ((ks * 2 + h) ^ cx) * 8;
                const half8 ah0 = *(const half8*)&lds[rowA * 64 + so];
                const half8 ah1 = *(const half8*)&lds[(rowA + 32) * 64 + so];
                const half8 al0 = *(const half8*)&lds[8192 + rowA * 64 + so];
                const half8 al1 = *(const half8*)&lds[8192 + (rowA + 32) * 64 + so];
                const half8 bh0 = *(const half8*)&lds[16384 + rowB * 64 + so];
                const half8 bh1 = *(const half8*)&lds[16384 + (rowB + 32) * 64 + so];
                const half8 bl0 = *(const half8*)&lds[24576 + rowB * 64 + so];
                const half8 bl1 = *(const half8*)&lds[24576 + (rowB + 32) * 64 + so];

                accH00 = __builtin_amdgcn_mfma_f32_32x32x16_f16(ah0, bh0, accH00, 0, 0, 0);
                accC00 = __builtin_amdgcn_mfma_f32_32x32x16_f16(ah0, bl0, accC00, 0, 0, 0);
                accC00 = __builtin_amdgcn_mfma_f32_32x32x16_f16(al0, bh0, accC00, 0, 0, 0);

                accH01 = __builtin_amdgcn_mfma_f32_32x32x16_f16(ah0, bh1, accH01, 0, 0, 0);
                accC01 = __builtin_amdgcn_mfma_f32_32x32x16_f16(ah0, bl1, accC01, 0, 0, 0);
                accC01 = __builtin_amdgcn_mfma_f32_32x32x16_f16(al0, bh1, accC01, 0, 0, 0);

                accH10 = __builtin_amdgcn_mfma_f32_32x32x16_f16(ah1, bh0, accH10, 0, 0, 0);
                accC10 = __builtin_amdgcn_mfma_f32_32x32x16_f16(ah1, bl0, accC10, 0, 0, 0);
                accC10 = __builtin_amdgcn_mfma_f32_32x32x16_f16(al1, bh0, accC10, 0, 0, 0);

                accH11 = __builtin_amdgcn_mfma_f32_32x32x16_f16(ah1, bh1, accH11, 0, 0, 0);
                accC11 = __builtin_amdgcn_mfma_f32_32x32x16_f16(ah1, bl1, accC11, 0, 0, 0);
                accC11 = __builtin_amdgcn_mfma_f32_32x32x16_f16(al1, bh1, accC11, 0, 0, 0);
            }
            __syncthreads();
        }

        #pragma unroll
        for (int r = 0; r < 16; ++r) {
            const int codeSub = (r & 3) + ((r >> 2) << 3) + (h << 2);
            const int code0 = ntBase + wc * 64 + codeSub;
            const int code1 = code0 + 32;
            float v;
            v = fmaf(accC00[r], SC, accH00[r]);
            if (v > best0 || (v == best0 && code0 < bi0)) { best0 = v; bi0 = code0; }
            v = fmaf(accC10[r], SC, accH10[r]);
            if (v > best0 || (v == best0 && code1 < bi0)) { best0 = v; bi0 = code1; }
            v = fmaf(accC01[r], SC, accH01[r]);
            if (v > best1 || (v == best1 && code0 < bi1)) { best1 = v; bi1 = code0; }
            v = fmaf(accC11[r], SC, accH11[r]);
            if (v > best1 || (v == best1 && code1 < bi1)) { best1 = v; bi1 = code1; }
        }
    }

    {
        float ov = __shfl_xor(best0, 32); int oi = __shfl_xor(bi0, 32);
        if (ov > best0 || (ov == best0 && oi < bi0)) { best0 = ov; bi0 = oi; }
        ov = __shfl_xor(best1, 32); oi = __shfl_xor(bi1, 32);
        if (ov > best1 || (ov == best1 && oi < bi1)) { best1 = ov; bi1 = oi; }
    }
    if (h == 0) {
        mV[rowB][wc] = best0;      mI[rowB][wc] = bi0;
        mV[rowB + 32][wc] = best1; mI[rowB + 32][wc] = bi1;
    }
    __syncthreads();
    if (tid < 128) {
        const int slot = t * 128 + tid;
        if (slot < cnt) {
            float v0 = mV[tid][0]; int i0 = mI[tid][0];
            float v1 = mV[tid][1]; int i1 = mI[tid][1];
            float bv; int bidx;
            if (v1 > v0 || (v1 == v0 && i1 < i0)) { bv = v1; bidx = i1; }
            else                                  { bv = v0; bidx = i0; }
            atomicMax(&rkey[list[slot]], encodeKey(bv, bidx));
        }
    }
}

// fused: apply rescore result (rkey nonzero <=> flagged) + histogram
__global__ void k_hist2(const unsigned long long* __restrict__ rkey,
                        float* __restrict__ outIdx, int* __restrict__ cntI) {
    const int n = blockIdx.x * 256 + threadIdx.x;
    const unsigned long long key = rkey[n];
    float fidx = outIdx[n];
    if (key) {
        const int code = (int)(0xFFFFFFFFu - (unsigned)(key & 0xFFFFFFFFull));
        fidx = (float)code;
        outIdx[n] = fidx;
    }
    atomicAdd(&cntI[(int)fidx], 1);
}

// grid-strided gather + loss (2048 blocks, 16B/lane, 1 atomic/block)
__global__ void k_gather_loss(const float* __restrict__ X, const _Float16* __restrict__ Eh,
                              const _Float16* __restrict__ El, const float* __restrict__ outIdx,
                              float* __restrict__ qst, float* __restrict__ lossAcc) {
    const float SC = 1.0f / 4096.0f;
    float acc = 0.f;
    #pragma unroll
    for (int it = 0; it < 8; ++it) {
        const int e = (it * 2048 + blockIdx.x) * 256 + threadIdx.x;   // float4 index
        const int row = e >> 7;
        const int col = (e & 127) * 4;
        const int k = (int)outIdx[row];
        const float4 x = ((const float4*)X)[e];
        const half4v eh = *(const half4v*)&Eh[(size_t)k * DIM + col];
        const half4v el = *(const half4v*)&El[(size_t)k * DIM + col];
        const float q0 = (float)eh.x + (float)el.x * SC;
        const float q1 = (float)eh.y + (float)el.y * SC;
        const float q2 = (float)eh.z + (float)el.z * SC;
        const float q3 = (float)eh.w + (float)el.w * SC;
        const float d0 = q0 - x.x, d1 = q1 - x.y, d2 = q2 - x.z, d3 = q3 - x.w;
        float4 o; o.x = x.x + d0; o.y = x.y + d1; o.z = x.z + d2; o.w = x.w + d3;
        ((float4*)qst)[e] = o;
        acc += d0 * d0 + d1 * d1 + d2 * d2 + d3 * d3;
    }
    const float ls = block_sum_256(acc);
    if (threadIdx.x == 0) atomicAdd(lossAcc, ls);
}

// fused single-block: pre/nsum/new_cs + prefix-sum offsets + loss scalar
__global__ void k_stats(const float* __restrict__ emacs, const int* __restrict__ cntI,
                        const float* __restrict__ lossAcc, float* __restrict__ outCS,
                        float* __restrict__ csfin, int* __restrict__ offs,
                        float* __restrict__ outLoss) {
    __shared__ int ps[1024];
    __shared__ float fsh[17];
    const int t = threadIdx.x;
    float pre[8]; int ipref[8];
    float psum = 0.f; int isum = 0;
    #pragma unroll
    for (int j = 0; j < 8; ++j) {
        const int k = t * 8 + j;
        const int cv = cntI[k];
        ipref[j] = isum; isum += cv;
        const float p = emacs[k] * DECAYF + OMDF * (float)cv;
        pre[j] = p; psum += p;
    }
    float v = psum;
    #pragma unroll
    for (int off = 32; off; off >>= 1) v += __shfl_down(v, off);
    if ((t & 63) == 0) fsh[t >> 6] = v;
    ps[t] = isum;
    __syncthreads();
    if (t == 0) {
        float tot = 0.f;
        for (int i = 0; i < 16; ++i) tot += fsh[i];
        fsh[16] = tot;
    }
    for (int d = 1; d < 1024; d <<= 1) {
        const int x = (t >= d) ? ps[t - d] : 0;
        __syncthreads();
        ps[t] += x;
        __syncthreads();
    }
    const float n = fsh[16];
    const int base = ps[t] - isum;
    #pragma unroll
    for (int j = 0; j < 8; ++j) {
        const int k = t * 8 + j;
        offs[k] = base + ipref[j];
        const float cc = (pre[j] + EPSF) / (n + (float)KCODE * EPSF) * n;
        outCS[k] = cc;
        csfin[k] = cc;
    }
    if (t == 0) *outLoss = COMMITF * (*lossAcc) / (float)(NROWS * DIM);
}

__global__ void k_bin(const float* __restrict__ outIdx, const int* __restrict__ offs,
                      int* __restrict__ cursor, int* __restrict__ perm) {
    const int n = blockIdx.x * 256 + threadIdx.x;
    const int k = (int)outIdx[n];
    const int pos = offs[k] + atomicAdd(&cursor[k], 1);
    perm[pos] = n;
}

// one block per code: dw accumulation + EMA weight + embedding, fused.
__global__ void k_dw_fused(const float* __restrict__ X, const float* __restrict__ inv_in,
                           const int* __restrict__ perm, const int* __restrict__ offs,
                           const int* __restrict__ cntI, const float* __restrict__ emaw,
                           const float* __restrict__ csfin,
                           float* __restrict__ outW, float* __restrict__ outE) {
    const int k = blockIdx.x;
    const int t = threadIdx.x;
    const int c = cntI[k];
    const int base = offs[k];
    float a0 = 0.f, a1 = 0.f;
    for (int i = 0; i < c; ++i) {
        const int row = perm[base + i];
        const float iv = inv_in[row];
        const float2 x = *(const float2*)&X[(size_t)row * DIM + t * 2];
        a0 = fmaf(x.x, iv, a0);
        a1 = fmaf(x.y, iv, a1);
    }
    const float2 w2 = *(const float2*)&emaw[(size_t)k * DIM + t * 2];
    const float w0 = w2.x * DECAYF + OMDF * a0;
    const float w1 = w2.y * DECAYF + OMDF * a1;
    float2 ow; ow.x = w0; ow.y = w1;
    *(float2*)&outW[(size_t)k * DIM + t * 2] = ow;
    const float cs = fmaxf(csfin[k], EPSF);
    float2 oe; oe.x = w0 / cs; oe.y = w1 / cs;
    *(float2*)&outE[(size_t)k * DIM + t * 2] = oe;
}

extern "C" void kernel_launch(void* const* d_in, const int* in_sizes, int n_in,
                              void* d_out, int out_size, void* d_ws, size_t ws_size,
                              hipStream_t stream) {
    const float* inputs    = (const float*)d_in[0];
    const float* embedding = (const float*)d_in[1];
    const float* emacs     = (const float*)d_in[2];
    const float* emaw      = (const float*)d_in[3];
    float* out = (float*)d_out;
    float* ws  = (float*)d_ws;

    float* inv_in  = ws;
    float* sV1     = ws + 32768;
    float* sV2     = ws + 163840;
    unsigned short* sI1 = (unsigned short*)(ws + 294912);
    int*   list    = (int*)(ws + 360448);
    int*   flagCnt = (int*)(ws + 393216);
    float* inv_emb = ws + 393280;
    _Float16* Xh   = (_Float16*)(ws + 401472);
    _Float16* Xl   = (_Float16*)(ws + 8790080);
    _Float16* Eh   = (_Float16*)(ws + 17178688);
    _Float16* El   = (_Float16*)(ws + 19275840);
    // overlays valid after k_top2_merge (inside dead sV1/sV2 region):
    unsigned long long* rkey = (unsigned long long*)(ws + 32768);
    int*   cntI    = (int*)(ws + 98304);
    int*   cursor  = (int*)(ws + 106496);
    float* lossAcc = ws + 114688;
    float* csfin   = ws + 122884;
    int*   offs    = (int*)(ws + 131076);
    int*   perm    = (int*)(ws + 139268);

    float* outQst  = out;
    float* outLoss = out + 16777216;
    float* outIdx  = out + 16777217;
    float* outCS   = out + 16809985;
    float* outW    = out + 16818177;
    float* outE    = out + 21012481;

    hipMemsetAsync(flagCnt, 0, sizeof(int), stream);
    k_norm_split<<<NROWS / 4, 256, 0, stream>>>(inputs, inv_in, Xh, Xl);
    k_norm_split<<<KCODE / 4, 256, 0, stream>>>(embedding, inv_emb, Eh, El);
    k_hi<<<dim3(NROWS / 128, 4), 256, 0, stream>>>(Xh, Eh, sV1, sV2, sI1);
    k_top2_merge<<<NROWS / 256, 256, 0, stream>>>(sV1, sV2, sI1, outIdx, list, flagCnt);
    // zero overlays: rkey(65536 fl) + cntI + cursor + lossAcc  (32768..114690)
    hipMemsetAsync(ws + 32768, 0, (size_t)81922 * sizeof(float), stream);
    k_rescore<<<4096, 256, 0, stream>>>(Xh, Xl, Eh, El, list, flagCnt, rkey);
    k_hist2<<<NROWS / 256, 256, 0, stream>>>(rkey, outIdx, cntI);
    k_gather_loss<<<2048, 256, 0, stream>>>(inputs, Eh, El, outIdx, outQst, lossAcc);
    k_stats<<<1, 1024, 0, stream>>>(emacs, cntI, lossAcc, outCS, csfin, offs, outLoss);
    k_bin<<<NROWS / 256, 256, 0, stream>>>(outIdx, offs, cursor, perm);
    k_dw_fused<<<KCODE, 256, 0, stream>>>(inputs, inv_in, perm, offs, cntI, emaw, csfin,
                                          outW, outE);
}